// Round 19
// baseline (29.416 us; speedup 1.0000x reference)
//
#include <hip/hip_runtime.h>
#include <math.h>

#define NN 18
#define T_STEPS 1280
#define T1LEN 1278   // T-2 (after conv1)
#define T2LEN 1276   // T-4 (after conv2)
#define TC2 46
#define NCHUNK2 ((T2LEN + TC2 - 1) / TC2)  // 28
#define NBLK (NCHUNK2 * NN)                // 504 (2 blocks/CU, all resident)
// counter line indices (x32 ints = 128B lines)
#define CIDX_ANODE(n) (n)            // 0..17   parts barrier
#define CIDX_CNODE(n) (18 + (n))     // 18..35  dot election
#define CIDX_D        36             // global election
#define CIDX_WGRP(g)  (37 + (g))     // 37..45  wprep groups (9 x 8 blocks)
#define CIDX_WFIN     46             // wprep done
#define NCNT 47

typedef __attribute__((ext_vector_type(8))) short short8;
typedef __attribute__((ext_vector_type(4))) float f32x4;

__device__ __forceinline__ unsigned short f2bf(float v) {
    unsigned u = __builtin_bit_cast(unsigned, v);
    u = u + 0x7fff + ((u >> 16) & 1);          // RNE
    return (unsigned short)(u >> 16);
}
__device__ __forceinline__ float bf2f(unsigned short h) {
    unsigned u = ((unsigned)h) << 16;
    return __builtin_bit_cast(float, u);
}
// swizzled ushort index for [row][c] bf16 tiles read as uint4 A-fragments (verified R3-R18)
__device__ __forceinline__ int swz(int row, int c) {
    return row * 64 + (((c >> 3) ^ (row & 7)) << 3) + (c & 7);
}
__device__ __forceinline__ float ratomic_ld(const float* p) {
    return __hip_atomic_load(p, __ATOMIC_RELAXED, __HIP_MEMORY_SCOPE_AGENT);
}
__device__ __forceinline__ void ratomic_st(float* p, float v) {
    __hip_atomic_store(p, v, __ATOMIC_RELAXED, __HIP_MEMORY_SCOPE_AGENT);
}
__device__ __forceinline__ void ratomic_stu(unsigned* p, unsigned v) {
    __hip_atomic_store(p, v, __ATOMIC_RELAXED, __HIP_MEMORY_SCOPE_AGENT);
}
__device__ __forceinline__ int radd(int* p) {
    return __hip_atomic_fetch_add(p, 1, __ATOMIC_RELAXED, __HIP_MEMORY_SCOPE_AGENT);
}
__device__ __forceinline__ int rld(const int* p) {
    return __hip_atomic_load(p, __ATOMIC_RELAXED, __HIP_MEMORY_SCOPE_AGENT);
}

// =========== single fused kernel; weight split folded in (R19); h in registers;
// T2 never materialized. Sync: relaxed-atomic protocol only (R12-R15 lessons):
// no acquire/release anywhere; per-node spin (R15); counters zeroed by a
// hipMemsetAsync dispatch preceding this kernel on the stream. ===========
__global__ __launch_bounds__(256, 2) void k_mega(const float* __restrict__ x,
        const float* __restrict__ w1a, const float* __restrict__ b1a,
        const float* __restrict__ w1b, const float* __restrict__ b1b,
        const float* __restrict__ w1c, const float* __restrict__ b1c,
        const float* __restrict__ cw, const float* __restrict__ cb,
        const float* __restrict__ w2a, const float* __restrict__ w2b,
        const float* __restrict__ w2c,
        unsigned short* __restrict__ WBhi, unsigned short* __restrict__ WBlo,
        const float* __restrict__ b2a, const float* __restrict__ b2b,
        const float* __restrict__ b2c,
        const float* __restrict__ gamma, const float* __restrict__ beta,
        const float* __restrict__ fcw, const float* __restrict__ fcb,
        float* parts, float* dpart, float* ndot, int* cnts,
        float* __restrict__ out) {
    __shared__ float xs[52];
    __shared__ uint4 t1H[384], t1L[384];   // 48 rows x 64 bf16 (swizzled)
    __shared__ uint4 t2H[400], t2L[400];   // 50 rows (48,49 zero)
    __shared__ float red1[256], red2[256];
    __shared__ float pl[2 * NCHUNK2];
    __shared__ int flagNode, flagAll;
    int b = blockIdx.x;
    int node = b / NCHUNK2, chunk = b % NCHUNK2;
    int t0 = chunk * TC2;                  // T2 time base; T1 rows t0..t0+47
    int tid = threadIdx.x;
    int l = tid & 63, w = tid >> 6;
    int co = w * 16 + (l & 15);

    // ---- PRODUCER PHASE (blocks 0..71): split conv2 weights -> WB (hi/lo pairs),
    //      publish via relaxed uint32 atomic stores (coherence point), then tree
    //      done-counter: 9 groups of 8 -> WFIN. Runs before any other work. ----
    if (b < 72) {
        int j = b * 256 + tid;             // 18432 uint32 slots per array
        int kh  = j & 15;                  // klocal/2
        int col = (j >> 4) % 192;
        int kb  = j / (192 * 16);
        int conv = col >> 6, cow = col & 63, k = kb >> 1;
        const float* wsrc = (conv == 0) ? w2a : (conv == 1 ? w2b : w2c);
        unsigned hi01 = 0, lo01 = 0;
        #pragma unroll
        for (int s2 = 0; s2 < 2; ++s2) {
            int klocal = 2 * kh + s2;
            int ci = (kb & 1) * 32 + klocal;
            float v = wsrc[cow * 192 + ci * 3 + k];
            unsigned short h = f2bf(v);
            unsigned short lo = f2bf(v - bf2f(h));
            hi01 |= ((unsigned)h)  << (16 * s2);
            lo01 |= ((unsigned)lo) << (16 * s2);
        }
        ratomic_stu(&((unsigned*)WBhi)[j], hi01);
        ratomic_stu(&((unsigned*)WBlo)[j], lo01);
        asm volatile("s_waitcnt vmcnt(0)" ::: "memory");
        __syncthreads();
        if (tid == 0) {
            int o = radd(&cnts[CIDX_WGRP(b >> 3) * 32]);
            if (o == 7) radd(&cnts[CIDX_WFIN * 32]);
        }
    }

    // ---- stage + normalize 50 x values (needed soonest) ----
    if (tid < 50) {
        int xt = t0 + tid;
        float v = (xt < T_STEPS) ? x[xt * NN + node] : 0.f;
        xs[tid] = v / fmaxf(fabsf(v), 1e-12f);
    }
    // ---- prefetch this thread's 12 fcw values (needed last; overlaps compute) ----
    float fwreg[12];
    #pragma unroll
    for (int mt = 0; mt < 3; ++mt) {
        #pragma unroll
        for (int r = 0; r < 4; ++r) {
            int tl2 = mt * 16 + (l >> 4) * 4 + r;
            int t = t0 + tl2;
            fwreg[mt * 4 + r] = (tl2 < TC2 && t < T2LEN)
                ? fcw[(t * NN + node) * 64 + co] : 0.f;
        }
    }
    __syncthreads();

    // ---- conv1 + GLU + relu -> t1 tile rows 0..47 (bf16 hi/lo, swizzled) ----
    {
        unsigned short* tH = (unsigned short*)t1H;
        unsigned short* tL = (unsigned short*)t1L;
        int c = l;
        float wa0 = w1a[c*3], wa1 = w1a[c*3+1], wa2 = w1a[c*3+2];
        float wb0 = w1b[c*3], wb1 = w1b[c*3+1], wb2 = w1b[c*3+2];
        float wc0 = w1c[c*3], wc1 = w1c[c*3+1], wc2 = w1c[c*3+2];
        float ba = b1a[c], bb = b1b[c], bc = b1c[c];
        #pragma unroll
        for (int j = 0; j < 12; ++j) {
            int r = w * 12 + j;            // local T1 row, time t0 + r
            float x0 = xs[r], x1 = xs[r + 1], x2 = xs[r + 2];
            float pa = fmaf(wa2, x2, fmaf(wa1, x1, fmaf(wa0, x0, ba)));
            float pb = fmaf(wb2, x2, fmaf(wb1, x1, fmaf(wb0, x0, bb)));
            float pc_ = fmaf(wc2, x2, fmaf(wc1, x1, fmaf(wc0, x0, bc)));
            float q = 1.0f / (1.0f + expf(-pb));
            float v = fmaxf(pa * q + pc_, 0.f);
            if (t0 + r >= T1LEN) v = 0.f;
            unsigned short hi = f2bf(v);
            int sw = swz(r, c);
            tH[sw] = hi;
            tL[sw] = f2bf(v - bf2f(hi));
        }
    }
    // ---- cheb B fragments from cw (verified) ----
    int d = w * 16 + (l & 15);
    short8 cbh[2], cbl[2];
    #pragma unroll
    for (int kb = 0; kb < 2; ++kb) {
        #pragma unroll
        for (int j = 0; j < 8; ++j) {
            float v = cw[(kb * 32 + (l >> 4) * 8 + j) * 64 + d];
            unsigned short hi = f2bf(v);
            cbh[kb][j] = (short)hi;
            cbl[kb][j] = (short)f2bf(v - bf2f(hi));
        }
    }
    __syncthreads();
    // ---- cheb MFMA: 3 M-tiles -> t2 tile rows 0..47; zero 48..49 ----
    {
        f32x4 acc1[3];
        #pragma unroll
        for (int mt = 0; mt < 3; ++mt) acc1[mt] = (f32x4){0.f,0.f,0.f,0.f};
        #pragma unroll
        for (int kb = 0; kb < 2; ++kb) {
            #pragma unroll
            for (int mt = 0; mt < 3; ++mt) {
                int row = mt * 16 + (l & 15);
                int cbi = kb * 4 + (l >> 4);
                int si = row * 8 + (cbi ^ (row & 7));
                short8 ah = __builtin_bit_cast(short8, t1H[si]);
                short8 al = __builtin_bit_cast(short8, t1L[si]);
                acc1[mt] = __builtin_amdgcn_mfma_f32_16x16x32_bf16(ah, cbh[kb], acc1[mt], 0, 0, 0);
                acc1[mt] = __builtin_amdgcn_mfma_f32_16x16x32_bf16(al, cbh[kb], acc1[mt], 0, 0, 0);
                acc1[mt] = __builtin_amdgcn_mfma_f32_16x16x32_bf16(ah, cbl[kb], acc1[mt], 0, 0, 0);
            }
        }
        float cbias = cb[d];
        unsigned short* tH = (unsigned short*)t2H;
        unsigned short* tL = (unsigned short*)t2L;
        #pragma unroll
        for (int mt = 0; mt < 3; ++mt) {
            #pragma unroll
            for (int r = 0; r < 4; ++r) {
                int row = mt * 16 + (l >> 4) * 4 + r;
                float v = fmaxf(acc1[mt][r] + cbias, 0.f);
                if (t0 + row >= T1LEN) v = 0.f;
                unsigned short hi = f2bf(v);
                int sw = swz(row, d);
                tH[sw] = hi;
                tL[sw] = f2bf(v - bf2f(hi));
            }
        }
        if (tid < 128) {                   // zero halo rows 48,49
            int row = 48 + (tid >> 6), c = tid & 63;
            int sw = swz(row, c);
            tH[sw] = 0; tL[sw] = 0;
        }
    }
    __syncthreads();
    // ---- wait for weight producers (no-wait in steady state: producers finished
    //      ~1us into the kernel; we've done ~2-3us of conv1+cheb since) ----
    if (tid == 0) {
        while (rld(&cnts[CIDX_WFIN * 32]) < 9)
            __builtin_amdgcn_s_sleep(2);
    }
    __syncthreads();
    // ---- conv2 MFMA (verified): h stays in registers ----
    float hval[12];
    float s_sum = 0.f, s_sq = 0.f;
    {
        const uint4* wbh = (const uint4*)WBhi;
        const uint4* wbl = (const uint4*)WBlo;
        f32x4 acc[3][3];
        #pragma unroll
        for (int mt = 0; mt < 3; ++mt)
            #pragma unroll
            for (int ct = 0; ct < 3; ++ct)
                acc[mt][ct] = (f32x4){0.f, 0.f, 0.f, 0.f};
        for (int kb = 0; kb < 6; ++kb) {
            short8 bh[3], bl[3];
            #pragma unroll
            for (int ct = 0; ct < 3; ++ct) {
                int col = (w + 4 * ct) * 16 + (l & 15);
                int gi = (kb * 192 + col) * 4 + (l >> 4);
                bh[ct] = __builtin_bit_cast(short8, wbh[gi]);
                bl[ct] = __builtin_bit_cast(short8, wbl[gi]);
            }
            #pragma unroll
            for (int mt = 0; mt < 3; ++mt) {
                int row = mt * 16 + (l & 15) + (kb >> 1);
                int cb2 = (kb & 1) * 4 + (l >> 4);
                int si = row * 8 + (cb2 ^ (row & 7));
                short8 ah = __builtin_bit_cast(short8, t2H[si]);
                short8 al = __builtin_bit_cast(short8, t2L[si]);
                acc[mt][0] = __builtin_amdgcn_mfma_f32_16x16x32_bf16(ah, bh[0], acc[mt][0], 0, 0, 0);
                acc[mt][1] = __builtin_amdgcn_mfma_f32_16x16x32_bf16(ah, bh[1], acc[mt][1], 0, 0, 0);
                acc[mt][2] = __builtin_amdgcn_mfma_f32_16x16x32_bf16(ah, bh[2], acc[mt][2], 0, 0, 0);
                acc[mt][0] = __builtin_amdgcn_mfma_f32_16x16x32_bf16(al, bh[0], acc[mt][0], 0, 0, 0);
                acc[mt][1] = __builtin_amdgcn_mfma_f32_16x16x32_bf16(al, bh[1], acc[mt][1], 0, 0, 0);
                acc[mt][2] = __builtin_amdgcn_mfma_f32_16x16x32_bf16(al, bh[2], acc[mt][2], 0, 0, 0);
                acc[mt][0] = __builtin_amdgcn_mfma_f32_16x16x32_bf16(ah, bl[0], acc[mt][0], 0, 0, 0);
                acc[mt][1] = __builtin_amdgcn_mfma_f32_16x16x32_bf16(ah, bl[1], acc[mt][1], 0, 0, 0);
                acc[mt][2] = __builtin_amdgcn_mfma_f32_16x16x32_bf16(ah, bl[2], acc[mt][2], 0, 0, 0);
            }
        }
        float ba = b2a[co], bb = b2b[co], bc = b2c[co];
        #pragma unroll
        for (int mt = 0; mt < 3; ++mt) {
            #pragma unroll
            for (int r = 0; r < 4; ++r) {
                int tl2 = mt * 16 + (l >> 4) * 4 + r;
                int t = t0 + tl2;
                float hv = 0.f;
                if (tl2 < TC2 && t < T2LEN) {
                    float P = acc[mt][0][r] + ba, Q = acc[mt][1][r] + bb, Cc = acc[mt][2][r] + bc;
                    float qs = 1.f / (1.f + expf(-Q));
                    hv = fmaxf(fmaf(P, qs, Cc), 0.f);
                    s_sum += hv;
                    s_sq = fmaf(hv, hv, s_sq);
                }
                hval[mt * 4 + r] = hv;
            }
        }
    }
    red1[tid] = s_sum; red2[tid] = s_sq;
    __syncthreads();
    for (int off = 128; off > 0; off >>= 1) {
        if (tid < off) { red1[tid] += red1[tid + off]; red2[tid] += red2[tid + off]; }
        __syncthreads();
    }
    // ---- publish partials + per-node relaxed spin (R15-validated) ----
    if (tid == 0) {
        ratomic_st(&parts[b * 2],     red1[0]);
        ratomic_st(&parts[b * 2 + 1], red2[0]);
        asm volatile("s_waitcnt vmcnt(0)" ::: "memory");   // stores at coherence point
        radd(&cnts[CIDX_ANODE(node) * 32]);
        while (rld(&cnts[CIDX_ANODE(node) * 32]) < NCHUNK2)
            __builtin_amdgcn_s_sleep(4);
    }
    __syncthreads();
    // ---- per-node stats (fixed order, deterministic) ----
    if (tid < 2 * NCHUNK2) pl[tid] = ratomic_ld(&parts[node * 2 * NCHUNK2 + tid]);
    __syncthreads();
    float s = 0.f, q = 0.f;
    #pragma unroll
    for (int i = 0; i < NCHUNK2; ++i) { s += pl[2 * i]; q += pl[2 * i + 1]; }
    float cntf = (float)(T2LEN * 64);
    float mean = s / cntf;
    float var = q / cntf - mean * mean;
    float istd = rsqrtf(var + 1e-5f);
    float g = gamma[node], bt = beta[node];
    // ---- BN + relu + dot: pure VALU (fcw already in registers) ----
    float acc = 0.f;
    #pragma unroll
    for (int mt = 0; mt < 3; ++mt) {
        #pragma unroll
        for (int r = 0; r < 4; ++r) {
            int tl2 = mt * 16 + (l >> 4) * 4 + r;
            int t = t0 + tl2;
            if (tl2 < TC2 && t < T2LEN) {
                float v = fmaxf((hval[mt * 4 + r] - mean) * istd * g + bt, 0.f);
                acc = fmaf(v, fwreg[mt * 4 + r], acc);
            }
        }
    }
    red1[tid] = acc;
    __syncthreads();
    for (int off = 128; off > 0; off >>= 1) {
        if (tid < off) red1[tid] += red1[tid + off];
        __syncthreads();
    }
    if (tid == 0) {
        ratomic_st(&dpart[b], red1[0]);
        asm volatile("s_waitcnt vmcnt(0)" ::: "memory");
        int o = radd(&cnts[CIDX_CNODE(node) * 32]);
        flagNode = (o == NCHUNK2 - 1);
    }
    __syncthreads();
    if (!flagNode) return;
    // ---- node-elected block: sum its node's 28 dparts (fixed tree order) ----
    {
        float v = (tid < NCHUNK2) ? ratomic_ld(&dpart[node * NCHUNK2 + tid]) : 0.f;
        red1[tid] = v;
        __syncthreads();
        for (int off = 128; off > 0; off >>= 1) {
            if (tid < off) red1[tid] += red1[tid + off];
            __syncthreads();
        }
        if (tid == 0) {
            ratomic_st(&ndot[node], red1[0]);
            asm volatile("s_waitcnt vmcnt(0)" ::: "memory");
            int o2 = radd(&cnts[CIDX_D * 32]);
            flagAll = (o2 == NN - 1);
        }
        __syncthreads();
    }
    if (!flagAll) return;
    // ---- global-elected block: sum 18 node dots (fixed tree order) ----
    {
        float v = (tid < NN) ? ratomic_ld(&ndot[tid]) : 0.f;
        red1[tid] = v;
        __syncthreads();
        for (int off = 128; off > 0; off >>= 1) {
            if (tid < off) red1[tid] += red1[tid + off];
            __syncthreads();
        }
        if (tid == 0) out[0] = red1[0] + fcb[0];
    }
}

extern "C" void kernel_launch(void* const* d_in, const int* in_sizes, int n_in,
                              void* d_out, int out_size, void* d_ws, size_t ws_size,
                              hipStream_t stream) {
    const float* x     = (const float*)d_in[0];
    // d_in[1] edge_index, d_in[2] edge_weight: unused (ChebConv K=1 -> identity only)
    const float* w1a   = (const float*)d_in[3];
    const float* b1a   = (const float*)d_in[4];
    const float* w1b   = (const float*)d_in[5];
    const float* b1b   = (const float*)d_in[6];
    const float* w1c   = (const float*)d_in[7];
    const float* b1c   = (const float*)d_in[8];
    const float* chw   = (const float*)d_in[9];
    const float* chb   = (const float*)d_in[10];
    const float* w2a   = (const float*)d_in[11];
    const float* b2a   = (const float*)d_in[12];
    const float* w2b   = (const float*)d_in[13];
    const float* b2b   = (const float*)d_in[14];
    const float* w2c   = (const float*)d_in[15];
    const float* b2c   = (const float*)d_in[16];
    const float* gamma = (const float*)d_in[17];
    const float* beta  = (const float*)d_in[18];
    const float* fcw   = (const float*)d_in[19];
    const float* fcb   = (const float*)d_in[20];
    float* out = (float*)d_out;

    char* base = (char*)d_ws;
    unsigned short* WBhi  = (unsigned short*)(base);           // 73728 B
    unsigned short* WBlo  = (unsigned short*)(base + 73728);   // 73728 B
    float*          parts = (float*)(base + 147456);           // 1008 f (pad 4096)
    float*          dpart = (float*)(base + 151552);           // 504 f (pad 2048)
    float*          ndot  = (float*)(base + 153600);           // 18 f (pad 128)
    int*            cnts  = (int*)(base + 153728);             // 47 x 128 B

    hipMemsetAsync(cnts, 0, NCNT * 128, stream);   // zero sync counters (graph-legal)
    k_mega<<<NBLK, 256, 0, stream>>>(
        x, w1a, b1a, w1b, b1b, w1c, b1c, chw, chb,
        w2a, w2b, w2c, WBhi, WBlo, b2a, b2b, b2c, gamma, beta, fcw, fcb,
        parts, dpart, ndot, cnts, out);
}

// Round 20
// 28.036 us; speedup vs baseline: 1.0492x; 1.0492x over previous
//
#include <hip/hip_runtime.h>
#include <math.h>

#define NN 18
#define T_STEPS 1280
#define T1LEN 1278   // T-2 (after conv1)
#define T2LEN 1276   // T-4 (after conv2)
#define PREPBLK 144  // 36864 / 256
#define TC2 46
#define NCHUNK2 ((T2LEN + TC2 - 1) / TC2)  // 28
#define NBLK (NCHUNK2 * NN)                // 504 (2 blocks/CU, all resident)

typedef __attribute__((ext_vector_type(8))) short short8;
typedef __attribute__((ext_vector_type(4))) float f32x4;

__device__ __forceinline__ unsigned short f2bf(float v) {
    unsigned u = __builtin_bit_cast(unsigned, v);
    u = u + 0x7fff + ((u >> 16) & 1);          // RNE
    return (unsigned short)(u >> 16);
}
__device__ __forceinline__ float bf2f(unsigned short h) {
    unsigned u = ((unsigned)h) << 16;
    return __builtin_bit_cast(float, u);
}
// swizzled ushort index for [row][c] bf16 tiles read as uint4 A-fragments (verified R3-R17)
__device__ __forceinline__ int swz(int row, int c) {
    return row * 64 + (((c >> 3) ^ (row & 7)) << 3) + (c & 7);
}
__device__ __forceinline__ float ratomic_ld(const float* p) {
    return __hip_atomic_load(p, __ATOMIC_RELAXED, __HIP_MEMORY_SCOPE_AGENT);
}
__device__ __forceinline__ void ratomic_st(float* p, float v) {
    __hip_atomic_store(p, v, __ATOMIC_RELAXED, __HIP_MEMORY_SCOPE_AGENT);
}

// =========== K0: conv2 weight hi/lo split (verified R3) + counter zeroing ===========
__global__ void k_wprep(const float* __restrict__ wa, const float* __restrict__ wb,
                        const float* __restrict__ wc,
                        unsigned short* __restrict__ WBhi, unsigned short* __restrict__ WBlo,
                        int* __restrict__ cnts) {
    int i = blockIdx.x * 256 + threadIdx.x;
    if (blockIdx.x == 0 && threadIdx.x < 38) cnts[threadIdx.x * 32] = 0;  // 128B-strided
    if (i >= 6 * 192 * 32) return;
    int klocal = i & 31;
    int col = (i >> 5) % 192;
    int kb = i / (192 * 32);
    int conv = col >> 6, co = col & 63;
    int k = kb >> 1, ci = (kb & 1) * 32 + klocal;
    const float* w = (conv == 0) ? wa : (conv == 1 ? wb : wc);
    float v = w[co * 192 + ci * 3 + k];
    unsigned short hi = f2bf(v);
    WBhi[i] = hi;
    WBlo[i] = f2bf(v - bf2f(hi));
}

// =========== K1: fused everything; h in registers; T2 never materialized.
// fcw PREFETCHED to registers at kernel entry (R17): the 5.9MB dot-weight read
// overlaps conv compute + spin wait instead of sitting on the post-barrier
// critical path. Sync: relaxed-atomic protocol (R13/R15), per-node spin only. ===========
__global__ __launch_bounds__(256, 2) void k_mega(const float* __restrict__ x,
        const float* __restrict__ w1a, const float* __restrict__ b1a,
        const float* __restrict__ w1b, const float* __restrict__ b1b,
        const float* __restrict__ w1c, const float* __restrict__ b1c,
        const float* __restrict__ cw, const float* __restrict__ cb,
        const unsigned short* __restrict__ WBhi, const unsigned short* __restrict__ WBlo,
        const float* __restrict__ b2a, const float* __restrict__ b2b,
        const float* __restrict__ b2c,
        const float* __restrict__ gamma, const float* __restrict__ beta,
        const float* __restrict__ fcw, const float* __restrict__ fcb,
        float* parts, float* dpart, float* ndot, int* cnts,
        float* __restrict__ out) {
    __shared__ float xs[52];
    __shared__ uint4 t1H[384], t1L[384];   // 48 rows x 64 bf16 (swizzled)
    __shared__ uint4 t2H[400], t2L[400];   // 50 rows (48,49 zero)
    __shared__ float red1[256], red2[256];
    __shared__ float pl[2 * NCHUNK2];
    __shared__ int flagNode, flagAll;
    int b = blockIdx.x;
    int node = b / NCHUNK2, chunk = b % NCHUNK2;
    int t0 = chunk * TC2;                  // T2 time base; T1 rows t0..t0+47
    int tid = threadIdx.x;
    int l = tid & 63, w = tid >> 6;
    int co = w * 16 + (l & 15);
    int* cntA = cnts + node * 32;          // per-node parts barrier (28 contenders)
    int* cntC = cnts + (19 + node) * 32;   // per-node dot election (28 contenders)
    int* cntD = cnts + 37 * 32;            // global dot election (18 contenders)

    // ---- EARLY: prefetch this thread's 12 fcw values (independent of all compute;
    //      loads complete during conv/MFMA work and the spin wait) ----
    float fwreg[12];
    #pragma unroll
    for (int mt = 0; mt < 3; ++mt) {
        #pragma unroll
        for (int r = 0; r < 4; ++r) {
            int tl2 = mt * 16 + (l >> 4) * 4 + r;
            int t = t0 + tl2;
            fwreg[mt * 4 + r] = (tl2 < TC2 && t < T2LEN)
                ? fcw[(t * NN + node) * 64 + co] : 0.f;
        }
    }

    // ---- stage + normalize 50 x values for this node ----
    if (tid < 50) {
        int xt = t0 + tid;
        float v = (xt < T_STEPS) ? x[xt * NN + node] : 0.f;
        xs[tid] = v / fmaxf(fabsf(v), 1e-12f);
    }
    __syncthreads();

    // ---- conv1 + GLU + relu -> t1 tile rows 0..47 (bf16 hi/lo, swizzled) ----
    {
        unsigned short* tH = (unsigned short*)t1H;
        unsigned short* tL = (unsigned short*)t1L;
        int c = l;
        float wa0 = w1a[c*3], wa1 = w1a[c*3+1], wa2 = w1a[c*3+2];
        float wb0 = w1b[c*3], wb1 = w1b[c*3+1], wb2 = w1b[c*3+2];
        float wc0 = w1c[c*3], wc1 = w1c[c*3+1], wc2 = w1c[c*3+2];
        float ba = b1a[c], bb = b1b[c], bc = b1c[c];
        #pragma unroll
        for (int j = 0; j < 12; ++j) {
            int r = w * 12 + j;            // local T1 row, time t0 + r
            float x0 = xs[r], x1 = xs[r + 1], x2 = xs[r + 2];
            float pa = fmaf(wa2, x2, fmaf(wa1, x1, fmaf(wa0, x0, ba)));
            float pb = fmaf(wb2, x2, fmaf(wb1, x1, fmaf(wb0, x0, bb)));
            float pc_ = fmaf(wc2, x2, fmaf(wc1, x1, fmaf(wc0, x0, bc)));
            float q = 1.0f / (1.0f + expf(-pb));
            float v = fmaxf(pa * q + pc_, 0.f);
            if (t0 + r >= T1LEN) v = 0.f;
            unsigned short hi = f2bf(v);
            int sw = swz(r, c);
            tH[sw] = hi;
            tL[sw] = f2bf(v - bf2f(hi));
        }
    }
    // ---- cheb B fragments from cw (verified) ----
    int d = w * 16 + (l & 15);
    short8 cbh[2], cbl[2];
    #pragma unroll
    for (int kb = 0; kb < 2; ++kb) {
        #pragma unroll
        for (int j = 0; j < 8; ++j) {
            float v = cw[(kb * 32 + (l >> 4) * 8 + j) * 64 + d];
            unsigned short hi = f2bf(v);
            cbh[kb][j] = (short)hi;
            cbl[kb][j] = (short)f2bf(v - bf2f(hi));
        }
    }
    __syncthreads();
    // ---- cheb MFMA: 3 M-tiles -> t2 tile rows 0..47; zero 48..49 ----
    {
        f32x4 acc1[3];
        #pragma unroll
        for (int mt = 0; mt < 3; ++mt) acc1[mt] = (f32x4){0.f,0.f,0.f,0.f};
        #pragma unroll
        for (int kb = 0; kb < 2; ++kb) {
            #pragma unroll
            for (int mt = 0; mt < 3; ++mt) {
                int row = mt * 16 + (l & 15);
                int cbi = kb * 4 + (l >> 4);
                int si = row * 8 + (cbi ^ (row & 7));
                short8 ah = __builtin_bit_cast(short8, t1H[si]);
                short8 al = __builtin_bit_cast(short8, t1L[si]);
                acc1[mt] = __builtin_amdgcn_mfma_f32_16x16x32_bf16(ah, cbh[kb], acc1[mt], 0, 0, 0);
                acc1[mt] = __builtin_amdgcn_mfma_f32_16x16x32_bf16(al, cbh[kb], acc1[mt], 0, 0, 0);
                acc1[mt] = __builtin_amdgcn_mfma_f32_16x16x32_bf16(ah, cbl[kb], acc1[mt], 0, 0, 0);
            }
        }
        float cbias = cb[d];
        unsigned short* tH = (unsigned short*)t2H;
        unsigned short* tL = (unsigned short*)t2L;
        #pragma unroll
        for (int mt = 0; mt < 3; ++mt) {
            #pragma unroll
            for (int r = 0; r < 4; ++r) {
                int row = mt * 16 + (l >> 4) * 4 + r;
                float v = fmaxf(acc1[mt][r] + cbias, 0.f);
                if (t0 + row >= T1LEN) v = 0.f;
                unsigned short hi = f2bf(v);
                int sw = swz(row, d);
                tH[sw] = hi;
                tL[sw] = f2bf(v - bf2f(hi));
            }
        }
        if (tid < 128) {                   // zero halo rows 48,49
            int row = 48 + (tid >> 6), c = tid & 63;
            int sw = swz(row, c);
            tH[sw] = 0; tL[sw] = 0;
        }
    }
    __syncthreads();
    // ---- conv2 MFMA (verified): h stays in registers ----
    float hval[12];
    float s_sum = 0.f, s_sq = 0.f;
    {
        const uint4* wbh = (const uint4*)WBhi;
        const uint4* wbl = (const uint4*)WBlo;
        f32x4 acc[3][3];
        #pragma unroll
        for (int mt = 0; mt < 3; ++mt)
            #pragma unroll
            for (int ct = 0; ct < 3; ++ct)
                acc[mt][ct] = (f32x4){0.f, 0.f, 0.f, 0.f};
        for (int kb = 0; kb < 6; ++kb) {
            short8 bh[3], bl[3];
            #pragma unroll
            for (int ct = 0; ct < 3; ++ct) {
                int col = (w + 4 * ct) * 16 + (l & 15);
                int gi = (kb * 192 + col) * 4 + (l >> 4);
                bh[ct] = __builtin_bit_cast(short8, wbh[gi]);
                bl[ct] = __builtin_bit_cast(short8, wbl[gi]);
            }
            #pragma unroll
            for (int mt = 0; mt < 3; ++mt) {
                int row = mt * 16 + (l & 15) + (kb >> 1);
                int cb2 = (kb & 1) * 4 + (l >> 4);
                int si = row * 8 + (cb2 ^ (row & 7));
                short8 ah = __builtin_bit_cast(short8, t2H[si]);
                short8 al = __builtin_bit_cast(short8, t2L[si]);
                acc[mt][0] = __builtin_amdgcn_mfma_f32_16x16x32_bf16(ah, bh[0], acc[mt][0], 0, 0, 0);
                acc[mt][1] = __builtin_amdgcn_mfma_f32_16x16x32_bf16(ah, bh[1], acc[mt][1], 0, 0, 0);
                acc[mt][2] = __builtin_amdgcn_mfma_f32_16x16x32_bf16(ah, bh[2], acc[mt][2], 0, 0, 0);
                acc[mt][0] = __builtin_amdgcn_mfma_f32_16x16x32_bf16(al, bh[0], acc[mt][0], 0, 0, 0);
                acc[mt][1] = __builtin_amdgcn_mfma_f32_16x16x32_bf16(al, bh[1], acc[mt][1], 0, 0, 0);
                acc[mt][2] = __builtin_amdgcn_mfma_f32_16x16x32_bf16(al, bh[2], acc[mt][2], 0, 0, 0);
                acc[mt][0] = __builtin_amdgcn_mfma_f32_16x16x32_bf16(ah, bl[0], acc[mt][0], 0, 0, 0);
                acc[mt][1] = __builtin_amdgcn_mfma_f32_16x16x32_bf16(ah, bl[1], acc[mt][1], 0, 0, 0);
                acc[mt][2] = __builtin_amdgcn_mfma_f32_16x16x32_bf16(ah, bl[2], acc[mt][2], 0, 0, 0);
            }
        }
        float ba = b2a[co], bb = b2b[co], bc = b2c[co];
        #pragma unroll
        for (int mt = 0; mt < 3; ++mt) {
            #pragma unroll
            for (int r = 0; r < 4; ++r) {
                int tl2 = mt * 16 + (l >> 4) * 4 + r;
                int t = t0 + tl2;
                float hv = 0.f;
                if (tl2 < TC2 && t < T2LEN) {
                    float P = acc[mt][0][r] + ba, Q = acc[mt][1][r] + bb, Cc = acc[mt][2][r] + bc;
                    float qs = 1.f / (1.f + expf(-Q));
                    hv = fmaxf(fmaf(P, qs, Cc), 0.f);
                    s_sum += hv;
                    s_sq = fmaf(hv, hv, s_sq);
                }
                hval[mt * 4 + r] = hv;
            }
        }
    }
    red1[tid] = s_sum; red2[tid] = s_sq;
    __syncthreads();
    for (int off = 128; off > 0; off >>= 1) {
        if (tid < off) { red1[tid] += red1[tid + off]; red2[tid] += red2[tid + off]; }
        __syncthreads();
    }
    // ---- publish partials + PER-NODE relaxed spin (28 pollers/line, 18 lines) ----
    if (tid == 0) {
        ratomic_st(&parts[b * 2],     red1[0]);
        ratomic_st(&parts[b * 2 + 1], red2[0]);
        asm volatile("s_waitcnt vmcnt(0)" ::: "memory");   // stores at coherence point
        __hip_atomic_fetch_add(cntA, 1, __ATOMIC_RELAXED, __HIP_MEMORY_SCOPE_AGENT);
        while (__hip_atomic_load(cntA, __ATOMIC_RELAXED, __HIP_MEMORY_SCOPE_AGENT) < NCHUNK2)
            __builtin_amdgcn_s_sleep(4);
    }
    __syncthreads();
    // ---- per-node stats (fixed order, deterministic) ----
    if (tid < 2 * NCHUNK2) pl[tid] = ratomic_ld(&parts[node * 2 * NCHUNK2 + tid]);
    __syncthreads();
    float s = 0.f, q = 0.f;
    #pragma unroll
    for (int i = 0; i < NCHUNK2; ++i) { s += pl[2 * i]; q += pl[2 * i + 1]; }
    float cntf = (float)(T2LEN * 64);
    float mean = s / cntf;
    float var = q / cntf - mean * mean;
    float istd = rsqrtf(var + 1e-5f);
    float g = gamma[node], bt = beta[node];
    // ---- BN + relu + dot: pure VALU now (fcw already in registers) ----
    float acc = 0.f;
    #pragma unroll
    for (int mt = 0; mt < 3; ++mt) {
        #pragma unroll
        for (int r = 0; r < 4; ++r) {
            int tl2 = mt * 16 + (l >> 4) * 4 + r;
            int t = t0 + tl2;
            if (tl2 < TC2 && t < T2LEN) {
                float v = fmaxf((hval[mt * 4 + r] - mean) * istd * g + bt, 0.f);
                acc = fmaf(v, fwreg[mt * 4 + r], acc);
            }
        }
    }
    red1[tid] = acc;
    __syncthreads();
    for (int off = 128; off > 0; off >>= 1) {
        if (tid < off) red1[tid] += red1[tid + off];
        __syncthreads();
    }
    if (tid == 0) {
        ratomic_st(&dpart[b], red1[0]);
        asm volatile("s_waitcnt vmcnt(0)" ::: "memory");
        int o = __hip_atomic_fetch_add(cntC, 1, __ATOMIC_RELAXED, __HIP_MEMORY_SCOPE_AGENT);
        flagNode = (o == NCHUNK2 - 1);
    }
    __syncthreads();
    if (!flagNode) return;
    // ---- node-elected block: sum its node's 28 dparts (fixed tree order) ----
    {
        float v = (tid < NCHUNK2) ? ratomic_ld(&dpart[node * NCHUNK2 + tid]) : 0.f;
        red1[tid] = v;
        __syncthreads();
        for (int off = 128; off > 0; off >>= 1) {
            if (tid < off) red1[tid] += red1[tid + off];
            __syncthreads();
        }
        if (tid == 0) {
            ratomic_st(&ndot[node], red1[0]);
            asm volatile("s_waitcnt vmcnt(0)" ::: "memory");
            int o2 = __hip_atomic_fetch_add(cntD, 1, __ATOMIC_RELAXED, __HIP_MEMORY_SCOPE_AGENT);
            flagAll = (o2 == NN - 1);
        }
        __syncthreads();
    }
    if (!flagAll) return;
    // ---- global-elected block: sum 18 node dots (fixed tree order) ----
    {
        float v = (tid < NN) ? ratomic_ld(&ndot[tid]) : 0.f;
        red1[tid] = v;
        __syncthreads();
        for (int off = 128; off > 0; off >>= 1) {
            if (tid < off) red1[tid] += red1[tid + off];
            __syncthreads();
        }
        if (tid == 0) out[0] = red1[0] + fcb[0];
    }
}

extern "C" void kernel_launch(void* const* d_in, const int* in_sizes, int n_in,
                              void* d_out, int out_size, void* d_ws, size_t ws_size,
                              hipStream_t stream) {
    const float* x     = (const float*)d_in[0];
    // d_in[1] edge_index, d_in[2] edge_weight: unused (ChebConv K=1 -> identity only)
    const float* w1a   = (const float*)d_in[3];
    const float* b1a   = (const float*)d_in[4];
    const float* w1b   = (const float*)d_in[5];
    const float* b1b   = (const float*)d_in[6];
    const float* w1c   = (const float*)d_in[7];
    const float* b1c   = (const float*)d_in[8];
    const float* chw   = (const float*)d_in[9];
    const float* chb   = (const float*)d_in[10];
    const float* w2a   = (const float*)d_in[11];
    const float* b2a   = (const float*)d_in[12];
    const float* w2b   = (const float*)d_in[13];
    const float* b2b   = (const float*)d_in[14];
    const float* w2c   = (const float*)d_in[15];
    const float* b2c   = (const float*)d_in[16];
    const float* gamma = (const float*)d_in[17];
    const float* beta  = (const float*)d_in[18];
    const float* fcw   = (const float*)d_in[19];
    const float* fcb   = (const float*)d_in[20];
    float* out = (float*)d_out;

    char* base = (char*)d_ws;
    unsigned short* WBhi  = (unsigned short*)(base);           // 73728 B
    unsigned short* WBlo  = (unsigned short*)(base + 73728);   // 73728 B
    float*          parts = (float*)(base + 147456);           // 1008 f (pad 4096)
    float*          dpart = (float*)(base + 151552);           // 504 f (pad 2048)
    float*          ndot  = (float*)(base + 153600);           // 18 f (pad 128)
    int*            cnts  = (int*)(base + 153728);             // 38 x 128 B

    k_wprep<<<PREPBLK, 256, 0, stream>>>(w2a, w2b, w2c, WBhi, WBlo, cnts);
    k_mega<<<NBLK, 256, 0, stream>>>(
        x, w1a, b1a, w1b, b1b, w1c, b1c, chw, chb,
        WBhi, WBlo, b2a, b2b, b2c, gamma, beta, fcw, fcb,
        parts, dpart, ndot, cnts, out);
}